// Round 8
// baseline (762.630 us; speedup 1.0000x reference)
//
#include <hip/hip_runtime.h>

#define B_TOT 65536
#define SEQ   32

typedef __bf16 bf16_8 __attribute__((ext_vector_type(8)));
typedef float  float4v __attribute__((ext_vector_type(4)));
typedef float  float2v __attribute__((ext_vector_type(2)));

#define SC1 (-1.4426950408889634f)   // -log2(e): i,f,o gate rows
#define SC2 (-2.8853900817779268f)   // -2*log2(e): g gate rows (and tanh(c2))

__device__ inline unsigned short f2bf(float f){
    unsigned u = __builtin_bit_cast(unsigned, f);
    u += 0x7FFFu + ((u >> 16) & 1u);           // round-to-nearest-even
    return (unsigned short)(u >> 16);
}

__device__ inline float2v v_exp2(float2v x){
    float2v r; r[0] = __builtin_amdgcn_exp2f(x[0]); r[1] = __builtin_amdgcn_exp2f(x[1]); return r;
}
__device__ inline float2v v_rcp(float2v x){
    float2v r; r[0] = __builtin_amdgcn_rcpf(x[0]); r[1] = __builtin_amdgcn_rcpf(x[1]); return r;
}
__device__ inline float2v v_fma(float2v a, float2v b, float2v c){
    float2v r; r[0] = __builtin_fmaf(a[0], b[0], c[0]); r[1] = __builtin_fmaf(a[1], b[1], c[1]); return r;
}

// ---- prep: W_eff = w_hh.T + w_pos.T @ (w_emb.T @ w_ih.T); biases folded;
// rows pre-scaled by -log2e (i,f,o) / -2log2e (g) so exp2 needs no mul. ----
__global__ void prep_kernel(const float* __restrict__ w_ih,
                            const float* __restrict__ w_hh,
                            const float* __restrict__ b_ih,
                            const float* __restrict__ b_hh,
                            const float* __restrict__ w_emb,
                            const float* __restrict__ b_emb,
                            const float* __restrict__ w_pos,
                            const float* __restrict__ b_pos,
                            unsigned short* __restrict__ weff,
                            float* __restrict__ beff,
                            float* __restrict__ m2,
                            unsigned short* __restrict__ wposA)
{
    int n = threadIdx.x;                       // 512 threads, one gate row each
    float m20 = 0.f, m21 = 0.f, bi = 0.f;
    for (int e = 0; e < 64; ++e){
        float wv = w_ih[n*64 + e];
        m20 += w_emb[e*2 + 0] * wv;
        m21 += w_emb[e*2 + 1] * wv;
        bi  += b_emb[e] * wv;
    }
    float sc = ((n >> 7) == 2) ? SC2 : SC1;    // gate order [i,f,g,o]
    m2[n]       = m20 * sc;
    m2[512 + n] = m21 * sc;
    beff[n] = (b_ih[n] + b_hh[n] + bi + b_pos[0]*m20 + b_pos[1]*m21) * sc;
    for (int k = 0; k < 128; ++k){
        float wv = w_hh[n*128 + k] + w_pos[k]*m20 + w_pos[128 + k]*m21;
        weff[n*128 + k] = f2bf(wv * sc);
    }
    if (n < 256) wposA[n] = f2bf(w_pos[n]);    // unscaled: rel path
    for (int idx = n; idx < 14*128; idx += 512) wposA[256 + idx] = 0;
}

// ---- main decoder: PRODUCER/CONSUMER wave specialization, v2.
// Same structure as round 7; fix = __launch_bounds__(512,1) so the compiler
// may allocate up to 512 VGPRs (round 7's (512,2) capped at 128 -> producer
// spilled wA to scratch: +112GB writes, both pipes starved). LDS (94KB)
// already pins 1 block/CU = 8 waves = 2/SIMD (1 producer + 1 consumer).
// Bias also hoisted to producer registers (budget now allows). ----
__global__ __launch_bounds__(512, 1) void dec_kernel(
    const float* __restrict__ lpr,             // (B,2)
    const float* __restrict__ hh,              // (B,128)
    const float* __restrict__ ch,              // (B,128)
    const float* __restrict__ b_pos,           // (2)
    const unsigned short* __restrict__ wposA,  // (16,128) bf16
    const unsigned short* __restrict__ weff,   // (512,128) bf16 pre-scaled
    const float* __restrict__ beff,            // (512) pre-scaled
    const float* __restrict__ m2,              // (2,512) pre-scaled
    float* __restrict__ out)                   // rels (32,B,2) ++ h (B,128)
{
    extern __shared__ __align__(16) char smem[];
    float* gacc0 = (float*)smem;                              // [16][512] f32 gates, tile A (16B-chunk XOR swizzle)
    float* gacc1 = (float*)(smem + 32768);                    // tile B
    unsigned short* lh0 = (unsigned short*)(smem + 65536);    // [16][152] bf16 h, tile A
    unsigned short* lh1 = (unsigned short*)(smem + 70400);    // tile B
    float* ubuf = (float*)(smem + 75264);                     // [32][2]
    float* hsh  = (float*)(smem + 75520);                     // [32][132] final-h staging

    const int tid  = threadIdx.x;
    const int w    = tid >> 6;                 // 0..7; SIMD = w & 3 (round-robin)
    const int lane = tid & 63;
    const int q    = lane >> 4;
    const int l    = lane & 15;
    const int row0 = blockIdx.x << 5;          // 32 batches per block
    const bool PROD = (w < 4);

    const float2v one2 = {1.f, 1.f};
    const float2v sc22 = {SC2, SC2};

    // ---- init: lh0/lh1 <- h0 (bf16, RTNE cast = identical to reg path) ----
    {
        int X   = tid >> 8;
        int rid = tid & 255;
        int il  = rid & 15;
        int iu0 = (rid >> 4) << 3;
        const float* ph = hh + ((row0 + (X << 4) + il) << 7) + iu0;
        float4v h0 = *(const float4v*)ph;
        float4v h1 = *(const float4v*)(ph + 4);
        bf16_8 t;
        t[0]=(__bf16)h0[0]; t[1]=(__bf16)h0[1]; t[2]=(__bf16)h0[2]; t[3]=(__bf16)h0[3];
        t[4]=(__bf16)h1[0]; t[5]=(__bf16)h1[1]; t[6]=(__bf16)h1[2]; t[7]=(__bf16)h1[3];
        unsigned short* lhp = X ? lh1 : lh0;
        *(bf16_8*)&lhp[il*152 + iu0] = t;
    }

    // ---- role-resident state ----
    bf16_8 wA[8][4];                // producers: 128 gate rows each
    float4v bias4[8];               // producers: bias resident
    bf16_8 wpA[4];
    float bp0 = 0.f, bp1 = 0.f;
    float2v cstA[4], cstB[4];       // consumers: c-state, 8 units x 2 tiles
    int ug = 0, u0 = 0;

    if (PROD){
#pragma unroll
        for (int t8 = 0; t8 < 8; ++t8){
            int nbase = ((t8 >> 1) << 7) + (w << 5) + ((t8 & 1) << 4);
            int gA = nbase + l;
#pragma unroll
            for (int kt = 0; kt < 4; ++kt)
                wA[t8][kt] = *(const bf16_8*)(weff + (gA << 7) + kt*32 + (q << 3));
            bias4[t8] = *(const float4v*)(beff + nbase + (q << 2));
        }
#pragma unroll
        for (int kt = 0; kt < 4; ++kt)
            wpA[kt] = *(const bf16_8*)(wposA + (l << 7) + kt*32 + (q << 3));
        bp0 = b_pos[0]; bp1 = b_pos[1];
    } else {
        int cw = w - 4;
        ug = (cw << 2) + q;         // 0..15
        u0 = ug << 3;               // unit base, 8 units/thread
        const float* pca = ch + ((row0 + l) << 7) + u0;
        const float* pcb = ch + ((row0 + 16 + l) << 7) + u0;
        float4v ca0 = *(const float4v*)pca;  float4v ca1 = *(const float4v*)(pca + 4);
        float4v cb0 = *(const float4v*)pcb;  float4v cb1 = *(const float4v*)(pcb + 4);
        cstA[0][0]=ca0[0]; cstA[0][1]=ca0[1]; cstA[1][0]=ca0[2]; cstA[1][1]=ca0[3];
        cstA[2][0]=ca1[0]; cstA[2][1]=ca1[1]; cstA[3][0]=ca1[2]; cstA[3][1]=ca1[3];
        cstB[0][0]=cb0[0]; cstB[0][1]=cb0[1]; cstB[1][0]=cb0[2]; cstB[1][1]=cb0[3];
        cstB[2][0]=cb1[0]; cstB[2][1]=cb1[1]; cstB[3][0]=cb1[2]; cstB[3][1]=cb1[3];
    }
    __syncthreads();

    // ---- producer phase: gates(X,t) = W_eff x h(X,t-1) + bias -> gacc;
    // duty wave also computes rel(X,t-1) (or ubuf at t==0) from the same b ----
    auto pphase = [&](const unsigned short* lhp, float* gp, int t, int X){
        bf16_8 b[4];
#pragma unroll
        for (int kt = 0; kt < 4; ++kt)
            b[kt] = *(const bf16_8*)&lhp[l*152 + kt*32 + (q << 3)];
        float4v a8[8];
#pragma unroll
        for (int t8 = 0; t8 < 8; ++t8)
            a8[t8] = __builtin_amdgcn_mfma_f32_16x16x32_bf16(wA[t8][0], b[0], bias4[t8], 0, 0, 0);
#pragma unroll
        for (int kt = 1; kt < 4; ++kt)
#pragma unroll
            for (int t8 = 0; t8 < 8; ++t8)
                a8[t8] = __builtin_amdgcn_mfma_f32_16x16x32_bf16(wA[t8][kt], b[kt], a8[t8], 0, 0, 0);
#pragma unroll
        for (int t8 = 0; t8 < 8; ++t8){
            int c = ((t8 >> 1) << 5) + (w << 3) + ((t8 & 1) << 2) + q;   // row/4
            *(float4v*)&gp[(l << 9) + ((c ^ (l & 7)) << 2)] = a8[t8];
        }
        if (w == (t & 3)){
            float4v r = {0.f, 0.f, 0.f, 0.f};
#pragma unroll
            for (int kt = 0; kt < 4; ++kt)
                r = __builtin_amdgcn_mfma_f32_16x16x32_bf16(wpA[kt], b[kt], r, 0, 0, 0);
            int batch = row0 + (X << 4) + l;
            if (t == 0){
                if (q == 0){
                    float2v lp = *(const float2v*)(lpr + (batch << 1));
                    ubuf[(((X << 4) + l) << 1) + 0] = lp[0] - (r[0] + bp0);
                    ubuf[(((X << 4) + l) << 1) + 1] = lp[1] - (r[1] + bp1);
                }
            } else if (q == 0){
                float2v rv; rv[0] = r[0] + bp0; rv[1] = r[1] + bp1;
                *(float2v*)(out + (t - 1)*(B_TOT*2) + (batch << 1)) = rv;
            }
        }
    };

    // rel for the last step (tail)
    auto prel = [&](const unsigned short* lhp, int X){
        bf16_8 b[4];
#pragma unroll
        for (int kt = 0; kt < 4; ++kt)
            b[kt] = *(const bf16_8*)&lhp[l*152 + kt*32 + (q << 3)];
        float4v r = {0.f, 0.f, 0.f, 0.f};
#pragma unroll
        for (int kt = 0; kt < 4; ++kt)
            r = __builtin_amdgcn_mfma_f32_16x16x32_bf16(wpA[kt], b[kt], r, 0, 0, 0);
        if (q == 0){
            int batch = row0 + (X << 4) + l;
            float2v rv; rv[0] = r[0] + bp0; rv[1] = r[1] + bp1;
            *(float2v*)(out + (SEQ - 1)*(B_TOT*2) + (batch << 1)) = rv;
        }
    };

    // ---- consumer phase: read gates f32, LSTM cell (verified round-2 math,
    // bit-identical), write h bf16 to lh (and f32 to hsh at the last step) ----
    auto elem = [&](const float* gp, float2v (&cst)[4],
                    unsigned short* lhp, int X, bool u0f, bool finalh){
        float4v gv[4][2];
#pragma unroll
        for (int g = 0; g < 4; ++g)
#pragma unroll
            for (int s = 0; s < 2; ++s){
                int c = (g << 5) + (ug << 1) + s;
                gv[g][s] = *(const float4v*)&gp[(l << 9) + ((c ^ (l & 7)) << 2)];
            }
        if (u0f){
            float u0v = ubuf[(((X << 4) + l) << 1) + 0];
            float u1v = ubuf[(((X << 4) + l) << 1) + 1];
#pragma unroll
            for (int g = 0; g < 4; ++g)
#pragma unroll
                for (int s = 0; s < 2; ++s){
                    const float* mp = m2 + (g << 7) + u0 + (s << 2);
                    float4v ma = *(const float4v*)mp;
                    float4v mb = *(const float4v*)(mp + 512);
#pragma unroll
                    for (int i = 0; i < 4; ++i)
                        gv[g][s][i] += u0v*ma[i] + u1v*mb[i];
                }
        }
        bf16_8 hv;
#pragma unroll
        for (int p = 0; p < 4; ++p){
            int s = p >> 1, o = (p & 1) << 1;
            float2v iv = {gv[0][s][o], gv[0][s][o + 1]};
            float2v fv = {gv[1][s][o], gv[1][s][o + 1]};
            float2v gz = {gv[2][s][o], gv[2][s][o + 1]};
            float2v ov = {gv[3][s][o], gv[3][s][o + 1]};
            float2v ei = v_exp2(iv);                  // e^{-i}
            float2v ef = v_exp2(fv);                  // e^{-f}
            float2v eg = v_exp2(gz);                  // e^{-2g}
            float2v pi_ = ei + one2;
            float2v pf  = ef + one2;
            float2v pg  = eg + one2;
            float2v mg  = one2 - eg;
            float2v t2  = pi_ * pg;
            float2v den = pf * t2;
            float2v num = v_fma(cst[p], t2, pf * mg);
            float2v c2  = num * v_rcp(den);
            float2v eo  = v_exp2(ov);                 // e^{-o}
            float2v ec  = v_exp2(c2 * sc22);          // e^{-2c2}
            float2v po  = eo + one2;
            float2v pc  = ec + one2;
            float2v mc  = one2 - ec;
            float2v h2  = mc * v_rcp(po * pc);
            cst[p] = c2;
            hv[2*p]     = (__bf16)h2[0];
            hv[2*p + 1] = (__bf16)h2[1];
            if (finalh)
                *(float2v*)&hsh[((X << 4) + l)*132 + u0 + 2*p] = h2;
        }
        *(bf16_8*)&lhp[l*152 + u0] = hv;
    };

    // ---- ping-pong main loop ----
    for (int t = 0; t < SEQ; ++t){
        // phase 1: P gates(A,t) || C elem(B,t-1)
        if (PROD)       pphase(lh0, gacc0, t, 0);
        else if (t > 0) elem(gacc1, cstB, lh1, 1, t == 1, false);
        __syncthreads();
        // phase 2: P gates(B,t) || C elem(A,t)
        if (PROD) pphase(lh1, gacc1, t, 1);
        else      elem(gacc0, cstA, lh0, 0, t == 0, t == SEQ - 1);
        __syncthreads();
    }
    // tail 1: P rel(A,31) || C elem(B,31)
    if (PROD){
        if (w == 0) prel(lh0, 0);
    } else {
        elem(gacc1, cstB, lh1, 1, false, true);
    }
    __syncthreads();
    // tail 2: P rel(B,31)
    if (PROD && w == 1) prel(lh1, 1);
    __syncthreads();

    // ---- coalesced final-h store ----
    {
        int r = tid >> 4, c8 = (tid & 15) << 3;
        float4v v0 = *(const float4v*)&hsh[r*132 + c8];
        float4v v1 = *(const float4v*)&hsh[r*132 + c8 + 4];
        float* po = out + SEQ*B_TOT*2 + ((row0 + r) << 7) + c8;
        *(float4v*)po = v0;
        *(float4v*)(po + 4) = v1;
    }
}

extern "C" void kernel_launch(void* const* d_in, const int* in_sizes, int n_in,
                              void* d_out, int out_size, void* d_ws, size_t ws_size,
                              hipStream_t stream)
{
    (void)in_sizes; (void)n_in; (void)out_size; (void)ws_size;

    const float* lpr   = (const float*)d_in[1];
    const float* hh    = (const float*)d_in[2];
    const float* ch    = (const float*)d_in[3];
    const float* w_ih  = (const float*)d_in[5];
    const float* w_hh  = (const float*)d_in[6];
    const float* b_ih  = (const float*)d_in[7];
    const float* b_hh  = (const float*)d_in[8];
    const float* w_emb = (const float*)d_in[9];
    const float* b_emb = (const float*)d_in[10];
    const float* w_pos = (const float*)d_in[11];
    const float* b_pos = (const float*)d_in[12];

    unsigned short* weff  = (unsigned short*)d_ws;                     // 512*128 bf16
    float* beff           = (float*)((char*)d_ws + 131072);            // 512 f32
    float* m2             = (float*)((char*)d_ws + 131072 + 2048);     // 1024 f32
    unsigned short* wposA = (unsigned short*)((char*)d_ws + 131072 + 2048 + 4096); // 16*128 bf16

    static bool attr_set = false;
    if (!attr_set){
        (void)hipFuncSetAttribute((const void*)dec_kernel,
                                  hipFuncAttributeMaxDynamicSharedMemorySize,
                                  96*1024);
        attr_set = true;
    }

    hipLaunchKernelGGL(prep_kernel, dim3(1), dim3(512), 0, stream,
                       w_ih, w_hh, b_ih, b_hh, w_emb, b_emb, w_pos, b_pos,
                       weff, beff, m2, wposA);
    hipLaunchKernelGGL(dec_kernel, dim3(B_TOT/32), dim3(512), 94464, stream,
                       lpr, hh, ch, b_pos, wposA, weff, beff, m2,
                       (float*)d_out);
}

// Round 9
// 488.089 us; speedup vs baseline: 1.5625x; 1.5625x over previous
//
#include <hip/hip_runtime.h>

#define B_TOT 65536
#define SEQ   32

typedef __bf16 bf16_8 __attribute__((ext_vector_type(8)));
typedef __bf16 bf16_4 __attribute__((ext_vector_type(4)));
typedef float  float4v __attribute__((ext_vector_type(4)));
typedef float  float2v __attribute__((ext_vector_type(2)));

#define SC1 (-1.4426950408889634f)   // -log2(e): i,f,o gate rows
#define SC2 (-2.8853900817779268f)   // -2*log2(e): g gate rows (and tanh(c2))

__device__ inline unsigned short f2bf(float f){
    unsigned u = __builtin_bit_cast(unsigned, f);
    u += 0x7FFFu + ((u >> 16) & 1u);           // round-to-nearest-even
    return (unsigned short)(u >> 16);
}

__device__ inline float2v v_exp2(float2v x){
    float2v r; r[0] = __builtin_amdgcn_exp2f(x[0]); r[1] = __builtin_amdgcn_exp2f(x[1]); return r;
}
__device__ inline float2v v_rcp(float2v x){
    float2v r; r[0] = __builtin_amdgcn_rcpf(x[0]); r[1] = __builtin_amdgcn_rcpf(x[1]); return r;
}
__device__ inline float2v v_fma(float2v a, float2v b, float2v c){
    float2v r; r[0] = __builtin_fmaf(a[0], b[0], c[0]); r[1] = __builtin_fmaf(a[1], b[1], c[1]); return r;
}

// ---- prep: W_eff = w_hh.T + w_pos.T @ (w_emb.T @ w_ih.T); biases folded;
// rows pre-scaled by -log2e (i,f,o) / -2log2e (g) so exp2 needs no mul. ----
__global__ void prep_kernel(const float* __restrict__ w_ih,
                            const float* __restrict__ w_hh,
                            const float* __restrict__ b_ih,
                            const float* __restrict__ b_hh,
                            const float* __restrict__ w_emb,
                            const float* __restrict__ b_emb,
                            const float* __restrict__ w_pos,
                            const float* __restrict__ b_pos,
                            unsigned short* __restrict__ weff,
                            float* __restrict__ beff,
                            float* __restrict__ m2,
                            unsigned short* __restrict__ wposA)
{
    int n = threadIdx.x;                       // 512 threads, one gate row each
    float m20 = 0.f, m21 = 0.f, bi = 0.f;
    for (int e = 0; e < 64; ++e){
        float wv = w_ih[n*64 + e];
        m20 += w_emb[e*2 + 0] * wv;
        m21 += w_emb[e*2 + 1] * wv;
        bi  += b_emb[e] * wv;
    }
    float sc = ((n >> 7) == 2) ? SC2 : SC1;    // gate order [i,f,g,o]
    m2[n]       = m20 * sc;
    m2[512 + n] = m21 * sc;
    beff[n] = (b_ih[n] + b_hh[n] + bi + b_pos[0]*m20 + b_pos[1]*m21) * sc;
    for (int k = 0; k < 128; ++k){
        float wv = w_hh[n*128 + k] + w_pos[k]*m20 + w_pos[128 + k]*m21;
        weff[n*128 + k] = f2bf(wv * sc);
    }
    if (n < 256) wposA[n] = f2bf(w_pos[n]);    // unscaled: rel path
    for (int idx = n; idx < 14*128; idx += 512) wposA[256 + idx] = 0;
}

// ---- main decoder: G^T = W_eff(A) x h^T(B); 16 rows/block, 4 waves.
// ROUND-2 STRUCTURE (best measured, 418 us) + BLOCK-LEVEL anti-phasing.
// Each block = 4 waves = 1 wave/SIMD; 2 blocks/CU -> each SIMD hosts one
// wave from each of two independent blocks. Identical deterministic code
// started simultaneously phase-locks them (both in gates, then both in
// elem -> pipes serialize). Delaying one block of each co-resident pair by
// ~half a step anti-phases them: gates(MFMA pipe) of one overlaps
// elem(VALU/trans pipe) of the other (m114: cross-wave MFMA||VALU = max,
// not sum). r6's version keyed off WAVE_ID -- an intra-block split that the
// block's own barrier absorbs. Selector must be per-BLOCK: dispatch fills
// CUs in 256-block passes (8 XCD x 32 CU), so co-resident blocks are i and
// i+256 -> phase = (blockIdx.x >> 8) & 1. ----
__global__ __launch_bounds__(256, 2) void dec_kernel(
    const float* __restrict__ lpr,             // (B,2)
    const float* __restrict__ hh,              // (B,128)
    const float* __restrict__ ch,              // (B,128)
    const float* __restrict__ b_pos,           // (2)
    const unsigned short* __restrict__ wposA,  // (16,128) bf16
    const unsigned short* __restrict__ weff,   // (512,128) bf16 pre-scaled
    const float* __restrict__ beff,            // (512) pre-scaled
    const float* __restrict__ m2,              // (2,512) pre-scaled
    float* __restrict__ out)                   // rels (32,B,2) ++ h (B,128)
{
    __shared__ __align__(16) unsigned short lh[2][16][152];  // stride 152: <=2-way banks
    __shared__ float ubuf[16][2];
    __shared__ __align__(16) float hsh[16][132];             // final-h staging

    const int tid  = threadIdx.x;
    const int w    = tid >> 6;
    const int lane = tid & 63;
    const int q    = lane >> 4;
    const int l    = lane & 15;
    const int row0 = blockIdx.x << 4;
    const int batch = row0 + l;

    const float2v one2 = {1.f, 1.f};
    const float2v sc22 = {SC2, SC2};

    // resident W_eff A-frags + bias float4s (bias used directly as MFMA C)
    bf16_8 wA[8][4];
    float4v bias4[8];
#pragma unroll
    for (int t8 = 0; t8 < 8; ++t8){
        int nbase = ((t8 >> 1) << 7) + 32*w + ((t8 & 1) << 4);
        int gA = nbase + l;
#pragma unroll
        for (int kt = 0; kt < 4; ++kt)
            wA[t8][kt] = *(const bf16_8*)(weff + (gA << 7) + kt*32 + (q << 3));
        bias4[t8] = *(const float4v*)(beff + nbase + (q << 2));
    }

    // w_pos A-frags (all waves; rel duty rotates)
    bf16_8 wpA[4];
#pragma unroll
    for (int kt = 0; kt < 4; ++kt)
        wpA[kt] = *(const bf16_8*)(wposA + (l << 7) + kt*32 + (q << 3));
    const float bp0 = b_pos[0], bp1 = b_pos[1];

    // c state: fp32 straight from global, kept as aligned pairs
    float2v cstp[2][2];
#pragma unroll
    for (int X = 0; X < 2; ++X){
        float4v cv = *(const float4v*)(ch + (batch << 7) + 32*w + 16*X + (q << 2));
        float2v clo = {cv[0], cv[1]};
        float2v chi = {cv[2], cv[3]};
        cstp[X][0] = clo;
        cstp[X][1] = chi;
    }

    // h0 B-frags straight from global (fp32 -> bf16)
    bf16_8 b[4];
#pragma unroll
    for (int kt = 0; kt < 4; ++kt){
        const float* ph = hh + (batch << 7) + kt*32 + (q << 3);
        float4v h0 = *(const float4v*)ph;
        float4v h1 = *(const float4v*)(ph + 4);
        bf16_8 t;
        t[0]=(__bf16)h0[0]; t[1]=(__bf16)h0[1]; t[2]=(__bf16)h0[2]; t[3]=(__bf16)h0[3];
        t[4]=(__bf16)h1[0]; t[5]=(__bf16)h1[1]; t[6]=(__bf16)h1[2]; t[7]=(__bf16)h1[3];
        b[kt] = t;
    }

    // wave0: r_{-1} = w_pos·h0 + b_pos ; u0' = lpr - r_{-1}
    if (w == 0){
        float4v r = {0.f, 0.f, 0.f, 0.f};
#pragma unroll
        for (int kt = 0; kt < 4; ++kt)
            r = __builtin_amdgcn_mfma_f32_16x16x32_bf16(wpA[kt], b[kt], r, 0, 0, 0);
        if (q == 0){
            float2v lp = *(const float2v*)(lpr + (batch << 1));
            ubuf[l][0] = lp[0] - (r[0] + bp0);
            ubuf[l][1] = lp[1] - (r[1] + bp1);
        }
    }
    __syncthreads();

    // ---- BLOCK-level anti-phase: odd-pass blocks start ~half a step late.
    // All 4 waves of the block sleep together -> intra-block barriers keep
    // the block coherent; the INTER-block offset persists (workloads are
    // identical and periodic, contention effects symmetric). ----
    if ((blockIdx.x >> 8) & 1){
        __builtin_amdgcn_s_sleep(30);   // ~1920 cyc ~ half of the 3900-cyc step
    }

    float4v acc[8];

    auto do_gates = [&](){
#pragma unroll
        for (int t8 = 0; t8 < 8; ++t8)     // kt=0 consumes bias as C: free init
            acc[t8] = __builtin_amdgcn_mfma_f32_16x16x32_bf16(wA[t8][0], b[0], bias4[t8], 0, 0, 0);
#pragma unroll
        for (int kt = 1; kt < 4; ++kt)
#pragma unroll
            for (int t8 = 0; t8 < 8; ++t8)
                acc[t8] = __builtin_amdgcn_mfma_f32_16x16x32_bf16(wA[t8][kt], b[kt], acc[t8], 0, 0, 0);
    };

    // merged-reciprocal LSTM cell, pairwise on native v2f32 (verified round 2)
    auto do_elem_write = [&](int buf, bool finalh){
#pragma unroll
        for (int X = 0; X < 2; ++X){
            bf16_4 hv;
#pragma unroll
            for (int p = 0; p < 2; ++p){
                float2v iv = {acc[0 + X][2*p], acc[0 + X][2*p + 1]};
                float2v fv = {acc[2 + X][2*p], acc[2 + X][2*p + 1]};
                float2v gv = {acc[4 + X][2*p], acc[4 + X][2*p + 1]};
                float2v ov = {acc[6 + X][2*p], acc[6 + X][2*p + 1]};
                float2v ei = v_exp2(iv);                  // e^{-i}
                float2v ef = v_exp2(fv);                  // e^{-f}
                float2v eg = v_exp2(gv);                  // e^{-2g}
                float2v pi_ = ei + one2;
                float2v pf  = ef + one2;
                float2v pg  = eg + one2;
                float2v mg  = one2 - eg;
                float2v t2  = pi_ * pg;
                float2v den = pf * t2;
                float2v num = v_fma(cstp[X][p], t2, pf * mg);
                float2v c2  = num * v_rcp(den);
                float2v eo  = v_exp2(ov);                 // e^{-o}
                float2v ec  = v_exp2(c2 * sc22);          // e^{-2c2}
                float2v po  = eo + one2;
                float2v pc  = ec + one2;
                float2v mc  = one2 - ec;
                float2v h2  = mc * v_rcp(po * pc);
                cstp[X][p] = c2;
                hv[2*p]     = (__bf16)h2[0];
                hv[2*p + 1] = (__bf16)h2[1];
                if (finalh){
                    int cb = 32*w + 16*X + (q << 2) + 2*p;
                    hsh[l][cb]     = h2[0];
                    hsh[l][cb + 1] = h2[1];
                }
            }
            *(bf16_4*)&lh[buf][l][32*w + 16*X + (q << 2)] = hv;   // packed b64
        }
    };

    auto reload_and_rel = [&](int buf, int t){
#pragma unroll
        for (int kt = 0; kt < 4; ++kt)
            b[kt] = *(const bf16_8*)&lh[buf][l][kt*32 + (q << 3)];
        if (w == (t & 3)){                    // rotate rel duty across waves
            float4v r = {0.f, 0.f, 0.f, 0.f};
#pragma unroll
            for (int kt = 0; kt < 4; ++kt)
                r = __builtin_amdgcn_mfma_f32_16x16x32_bf16(wpA[kt], b[kt], r, 0, 0, 0);
            if (q == 0){
                float2v rv;
                rv[0] = r[0] + bp0;
                rv[1] = r[1] + bp1;
                *(float2v*)(out + t*(B_TOT*2) + (batch << 1)) = rv;
            }
        }
    };

    // ---- step 0 (peeled: rank-2 input correction along the gate dim) ----
    do_gates();
    {
        float u0 = ubuf[l][0], u1 = ubuf[l][1];
#pragma unroll
        for (int t8 = 0; t8 < 8; ++t8){
            int g0 = ((t8 >> 1) << 7) + 32*w + ((t8 & 1) << 4) + (q << 2);
            float4v ma = *(const float4v*)(m2 + g0);
            float4v mb = *(const float4v*)(m2 + 512 + g0);
#pragma unroll
            for (int r4 = 0; r4 < 4; ++r4)
                acc[t8][r4] += u0*ma[r4] + u1*mb[r4];
        }
    }
    do_elem_write(1, false);
    __syncthreads();
    reload_and_rel(1, 0);

    // ---- steps 1..31 ----
    for (int t = 1; t < SEQ; ++t){
        do_gates();
        do_elem_write((t + 1) & 1, t == SEQ - 1);
        __syncthreads();
        reload_and_rel((t + 1) & 1, t);
    }

    // ---- coalesced final-h store: LDS-staged, contiguous 32 B per thread ----
    __syncthreads();
    {
        int r = tid >> 4, c8 = (tid & 15) << 3;
        float4v v0 = *(const float4v*)&hsh[r][c8];
        float4v v1 = *(const float4v*)&hsh[r][c8 + 4];
        float* po = out + SEQ*B_TOT*2 + ((row0 + r) << 7) + c8;
        *(float4v*)po = v0;
        *(float4v*)(po + 4) = v1;
    }
}

extern "C" void kernel_launch(void* const* d_in, const int* in_sizes, int n_in,
                              void* d_out, int out_size, void* d_ws, size_t ws_size,
                              hipStream_t stream)
{
    (void)in_sizes; (void)n_in; (void)out_size; (void)ws_size;

    const float* lpr   = (const float*)d_in[1];
    const float* hh    = (const float*)d_in[2];
    const float* ch    = (const float*)d_in[3];
    const float* w_ih  = (const float*)d_in[5];
    const float* w_hh  = (const float*)d_in[6];
    const float* b_ih  = (const float*)d_in[7];
    const float* b_hh  = (const float*)d_in[8];
    const float* w_emb = (const float*)d_in[9];
    const float* b_emb = (const float*)d_in[10];
    const float* w_pos = (const float*)d_in[11];
    const float* b_pos = (const float*)d_in[12];

    unsigned short* weff  = (unsigned short*)d_ws;                     // 512*128 bf16
    float* beff           = (float*)((char*)d_ws + 131072);            // 512 f32
    float* m2             = (float*)((char*)d_ws + 131072 + 2048);     // 1024 f32
    unsigned short* wposA = (unsigned short*)((char*)d_ws + 131072 + 2048 + 4096); // 16*128 bf16

    hipLaunchKernelGGL(prep_kernel, dim3(1), dim3(512), 0, stream,
                       w_ih, w_hh, b_ih, b_hh, w_emb, b_emb, w_pos, b_pos,
                       weff, beff, m2, wposA);
    hipLaunchKernelGGL(dec_kernel, dim3(B_TOT/16), dim3(256), 0, stream,
                       lpr, hh, ch, b_pos, wposA, weff, beff, m2,
                       (float*)d_out);
}